// Round 8
// baseline (114.204 us; speedup 1.0000x reference)
//
#include <hip/hip_runtime.h>
#include <math.h>

// Problem constants (B=4, S=2048, E=1024, A=64)
#define BATCH 4
#define SLEN  2048
#define EMB   1024
#define AH    64

typedef __attribute__((ext_vector_type(8))) short bf16x8;
typedef __attribute__((ext_vector_type(4))) float f32x4;

#define MFMA16(a, b, c) __builtin_amdgcn_mfma_f32_16x16x32_bf16((a), (b), (c), 0, 0, 0)

// async 16B global->LDS: zero VGPR cost, guaranteed in-flight batching.
// LDS dest = wave-uniform base + lane*16 (implicit).
__device__ __forceinline__ void async16(const void* g, void* l) {
  __builtin_amdgcn_global_load_lds(
      (const __attribute__((address_space(1))) unsigned int*)g,
      (__attribute__((address_space(3))) unsigned int*)l, 16, 0, 0);
}

__device__ __forceinline__ short f2bf(float x) {  // RNE
  union { float f; unsigned u; } v; v.f = x;
  unsigned r = v.u + 0x7fffu + ((v.u >> 16) & 1u);
  return (short)(r >> 16);
}
__device__ __forceinline__ float bf2f(short h) {
  union { unsigned u; float f; } v; v.u = ((unsigned)(unsigned short)h) << 16;
  return v.f;
}

// Truncate-split 8 fp32 -> bf16 hi (high16) + bf16 lo (trunc of residual).
__device__ __forceinline__ void split_trunc(float4 a0, float4 a1, bf16x8& hi, bf16x8& lo) {
  unsigned c[8] = {__float_as_uint(a0.x), __float_as_uint(a0.y), __float_as_uint(a0.z),
                   __float_as_uint(a0.w), __float_as_uint(a1.x), __float_as_uint(a1.y),
                   __float_as_uint(a1.z), __float_as_uint(a1.w)};
  union { bf16x8 v; unsigned d[4]; } H, L;
  H.d[0] = __builtin_amdgcn_perm(c[1], c[0], 0x07060302u);
  H.d[1] = __builtin_amdgcn_perm(c[3], c[2], 0x07060302u);
  H.d[2] = __builtin_amdgcn_perm(c[5], c[4], 0x07060302u);
  H.d[3] = __builtin_amdgcn_perm(c[7], c[6], 0x07060302u);
  unsigned e[8];
#pragma unroll
  for (int j = 0; j < 8; ++j)
    e[j] = __float_as_uint(__uint_as_float(c[j]) - __uint_as_float(c[j] & 0xffff0000u));
  L.d[0] = __builtin_amdgcn_perm(e[1], e[0], 0x07060302u);
  L.d[1] = __builtin_amdgcn_perm(e[3], e[2], 0x07060302u);
  L.d[2] = __builtin_amdgcn_perm(e[5], e[4], 0x07060302u);
  L.d[3] = __builtin_amdgcn_perm(e[7], e[6], 0x07060302u);
  hi = H.v; lo = L.v;
}

// Triangular chunk-slot offset: off(qt) = sum_{q<qt} (q/2 + 1)
__device__ __forceinline__ int slot_off(int qt) {
  return (qt == 0) ? 0 : qt + (((qt - 1) * (qt - 1)) >> 2);
}

// Kpack chunk layout (shorts), per (b, chunk of 128 keys), 24576 shorts = 48 KB:
//   [0,8192):      KBhi  [kb(8)][a32(2)][lane(64)][8]   S-MFMA B-frag, hi plane
//   [8192,16384):  KBlo  same, lo plane
//   [16384,24576): VB    [kc2(4)][nt(4)][lane(64)][8] PV-MFMA B-frag (hi only)
#define CH_SHORTS 24576

// ---------------------------------------------------------------------------
// A/B decomposition round: R7 = R0 + dGEMM + dFLASH regressed to 68us of
// kernel time (vs R0's 61). This build = R0 + dFLASH ONLY (gemm reverted to
// the verified double-buffered version). dur(new)-105.4 = dFLASH;
// dur(R7)-dur(new) = dGEMM.
// ---------------------------------------------------------------------------

// ---------------------------------------------------------------------------
// Kernel 0: pack Wk [64,1024] fp32 -> BpkG [kc(32)][nt(4)][pl(2)][lane(64)][8]
// ---------------------------------------------------------------------------
__global__ __launch_bounds__(256) void prep_wk_kernel(const float* __restrict__ Wk,
                                                      short* __restrict__ BpkG) {
  int tg = blockIdx.x * 256 + threadIdx.x;  // 8192 = 32kc * 4nt * 64lane
  int kc = tg >> 8, rem = tg & 255, nt = rem >> 6, lane = rem & 63;
  int n = nt * 16 + (lane & 15);
  int k = kc * 32 + (lane >> 4) * 8;
  const float* src = Wk + (size_t)n * EMB + k;
  float4 a0 = *(const float4*)src;
  float4 a1 = *(const float4*)(src + 4);
  bf16x8 hi, lo;
  split_trunc(a0, a1, hi, lo);
  short* dst = BpkG + ((size_t)(kc * 4 + nt) * 128 + lane) * 8;  // pl=0
  *(bf16x8*)dst = hi;
  *(bf16x8*)(dst + 512) = lo;  // pl=1
}

// ---------------------------------------------------------------------------
// Kernel 1 (R0-EXACT): K = emb @ Wk^T, DOUBLE-BUFFERED async LDS staging.
// 512 blocks x 256; BM=16, K-loop 16 steps of BK=64; two 20 KB buffers.
// ---------------------------------------------------------------------------
__global__ __launch_bounds__(256) void gemm_k_kernel(const float* __restrict__ emb,
                                                     const short* __restrict__ BpkG,
                                                     short* __restrict__ Kpack) {
  __shared__ __align__(16) char glds[40960];  // 2 x (4 KB emb + 16 KB bpk)

  const int t = threadIdx.x;
  const int w = t >> 6, l = t & 63, lm = l & 15, quad = l >> 4;
  const int nt = w;
  const int row0 = blockIdx.x * 16;

  auto stage = [&](int step, int bs) {
    char* base = glds + bs * 20480;
    float* eT = (float*)base;
    short* bT = (short*)(base + 4096);
    int rowl = 4 * w + (l >> 4);
    int du = (l & 15) ^ (rowl & 7);
    async16(emb + (size_t)(row0 + rowl) * EMB + step * 64 + du * 4, eT + w * 256);
    const short* bg = BpkG + (size_t)step * 8192;
#pragma unroll
    for (int u = 0; u < 4; ++u)
      async16(bg + (w * 4 + u) * 512 + l * 8, bT + (w * 4 + u) * 512);
  };

  f32x4 acc = {0.f, 0.f, 0.f, 0.f};
  stage(0, 0);
#pragma unroll
  for (int s = 0; s < 16; ++s) {
    __syncthreads();  // drains stage(s) (issued one compute-phase ago)
    if (s < 15) stage(s + 1, (s + 1) & 1);
    char* base = glds + (s & 1) * 20480;
    float* eT = (float*)base;
    short* bT = (short*)(base + 4096);
#pragma unroll
    for (int kc = 0; kc < 2; ++kc) {
      int du0 = kc * 8 + quad * 2;
      float4 a0 = *(const float4*)((char*)eT + lm * 256 + ((du0) ^ (lm & 7)) * 16);
      float4 a1 = *(const float4*)((char*)eT + lm * 256 + ((du0 + 1) ^ (lm & 7)) * 16);
      bf16x8 ahi, alo;
      split_trunc(a0, a1, ahi, alo);
      bf16x8 bhi = *(const bf16x8*)(bT + (((kc * 4 + nt) * 2 + 0) * 64 + l) * 8);
      bf16x8 blo = *(const bf16x8*)(bT + (((kc * 4 + nt) * 2 + 1) * 64 + l) * 8);
      acc = MFMA16(ahi, bhi, acc);
      acc = MFMA16(ahi, blo, acc);
      acc = MFMA16(alo, bhi, acc);
    }
  }

  // epilogue: C layout (row=quad*4+r, col a=nt*16+lm) -> Kpack fragment scatter
  const int a = nt * 16 + lm;
#pragma unroll
  for (int r = 0; r < 4; ++r) {
    int srow = row0 + quad * 4 + r;
    float v = acc[r];
    short h = f2bf(v);
    short lo2 = f2bf(v - bf2f(h));
    int bb = srow >> 11, si = srow & 2047, c = si >> 7, key = si & 127;
    int kb = key >> 4, klm = key & 15;
    size_t cb = (size_t)(bb * 16 + c) * CH_SHORTS;
    size_t kbo = (size_t)((kb * 2 + (a >> 5)) * 64 + ((a & 31) >> 3) * 16 + klm) * 8 + (a & 7);
    Kpack[cb + kbo] = h;
    Kpack[cb + 8192 + kbo] = lo2;
    size_t vbo = (size_t)(((key >> 5) * 4 + (a >> 4)) * 64 + ((key & 31) >> 3) * 16 + (a & 15)) * 8 + (key & 7);
    Kpack[cb + 16384 + vbo] = h;
  }
}

// ---------------------------------------------------------------------------
// Kernel 2 (R7 variant under test): flash partials at 4 blocks/CU.
// Stage only K-HI plane (16 KB LDS); lo-plane B-frags read directly from
// global (L2-hot, shared x4 waves x16 blocks). LDS 33.3 KB => 4/CU:
// 1088/1024 ~= 1.06 dispatch rounds (was 1.42 at 3/CU).
// ---------------------------------------------------------------------------
__global__ __launch_bounds__(256, 4) void flash_kernel(const short* __restrict__ Kpack,
                                                       short* __restrict__ OpartH,
                                                       float2* __restrict__ mlpart) {
  const int c = blockIdx.x, qt = blockIdx.y, b = blockIdx.z;
  if (2 * c > qt) return;

  __shared__ __align__(16) short KLs[8192];         // KBhi of chunk c (16 KB)
  __shared__ __align__(16) short Plds[4][16][132];  // per-wave P buffers (16.5 KB)

  const int t = threadIdx.x;
  const int w = t >> 6, l = t & 63, lm = l & 15, quad = l >> 4;
  const int k0 = c * 128;
  const int qr0 = qt * 64 + w * 16;

  const short* chunkG = Kpack + (size_t)(b * 16 + c) * CH_SHORTS;
  // stage KBhi: 16 slots x 1 KB
#pragma unroll
  for (int u = 0; u < 4; ++u) {
    int slot = w * 4 + u;
    async16(chunkG + slot * 512 + l * 8, KLs + slot * 512);
  }

  // Q fragments direct-to-VGPR (rows live in chunk qt>>1's KB region)
  const short* qG = Kpack + (size_t)(b * 16 + (qt >> 1)) * CH_SHORTS + ((qt & 1) * 4 + w) * 1024;
  bf16x8 qh0 = *(const bf16x8*)(qG + l * 8);
  bf16x8 qh1 = *(const bf16x8*)(qG + 512 + l * 8);
  bf16x8 ql0 = *(const bf16x8*)(qG + 8192 + l * 8);
  bf16x8 ql1 = *(const bf16x8*)(qG + 8192 + 512 + l * 8);

  // all 16 V fragments direct from global (coalesced 16B/lane)
  bf16x8 vf[4][4];
#pragma unroll
  for (int kc2 = 0; kc2 < 4; ++kc2)
#pragma unroll
    for (int nt = 0; nt < 4; ++nt)
      vf[kc2][nt] = *(const bf16x8*)(chunkG + 16384 + ((kc2 * 4 + nt) * 64 + l) * 8);

  __syncthreads();  // drains staging (Q/V register loads also complete)

  // S = Q K^T: 8 key-groups x 2 a-chunks x split(hh+hl+lh);
  // lo-plane B-frags straight from global.
  f32x4 sc[8];
#pragma unroll
  for (int kg = 0; kg < 8; ++kg) {
    bf16x8 bh0 = *(const bf16x8*)(KLs + ((kg * 2 + 0) * 64 + l) * 8);
    bf16x8 bh1 = *(const bf16x8*)(KLs + ((kg * 2 + 1) * 64 + l) * 8);
    bf16x8 bl0 = *(const bf16x8*)(chunkG + 8192 + ((kg * 2 + 0) * 64 + l) * 8);
    bf16x8 bl1 = *(const bf16x8*)(chunkG + 8192 + ((kg * 2 + 1) * 64 + l) * 8);
    f32x4 s = {0.f, 0.f, 0.f, 0.f};
    s = MFMA16(qh0, bh0, s);
    s = MFMA16(qh0, bl0, s);
    s = MFMA16(ql0, bh0, s);
    s = MFMA16(qh1, bh1, s);
    s = MFMA16(qh1, bl1, s);
    s = MFMA16(ql1, bh1, s);
    sc[kg] = s;
  }

  // mask + single-pass softmax (C layout: row=quad*4+r, col=kg*16+lm)
  float rm[4] = {-INFINITY, -INFINITY, -INFINITY, -INFINITY};
#pragma unroll
  for (int kg = 0; kg < 8; ++kg) {
    const int col = k0 + kg * 16 + lm;
#pragma unroll
    for (int r = 0; r < 4; ++r) {
      const int row = qr0 + quad * 4 + r;
      float v = sc[kg][r] * 0.125f;
      v = (col > row || v == 0.0f) ? -INFINITY : v;
      sc[kg][r] = v;
      rm[r] = fmaxf(rm[r], v);
    }
  }
  float m_i[4], l_i[4];
#pragma unroll
  for (int r = 0; r < 4; ++r) {
    for (int off = 1; off < 16; off <<= 1) rm[r] = fmaxf(rm[r], __shfl_xor(rm[r], off, 16));
    m_i[r] = rm[r];
  }
  float rs[4] = {0.f, 0.f, 0.f, 0.f};
#pragma unroll
  for (int kg = 0; kg < 8; ++kg)
#pragma unroll
    for (int r = 0; r < 4; ++r) {
      float p = (sc[kg][r] == -INFINITY) ? 0.f : __expf(sc[kg][r] - m_i[r]);
      sc[kg][r] = p;
      rs[r] += p;
    }
#pragma unroll
  for (int r = 0; r < 4; ++r) {
    for (int off = 1; off < 16; off <<= 1) rs[r] += __shfl_xor(rs[r], off, 16);
    l_i[r] = rs[r];
  }

  // P -> Plds (C layout -> A-operand layout), per-wave private, no barrier
#pragma unroll
  for (int kg = 0; kg < 8; ++kg)
#pragma unroll
    for (int r = 0; r < 4; ++r)
      Plds[w][quad * 4 + r][kg * 16 + lm] = f2bf(sc[kg][r]);

  // O = P V over 128 keys (V fragments already in registers)
  f32x4 o[4] = {{0.f,0.f,0.f,0.f},{0.f,0.f,0.f,0.f},{0.f,0.f,0.f,0.f},{0.f,0.f,0.f,0.f}};
#pragma unroll
  for (int kc2 = 0; kc2 < 4; ++kc2) {
    bf16x8 pf = *(const bf16x8*)&Plds[w][lm][kc2 * 32 + quad * 8];
#pragma unroll
    for (int nt = 0; nt < 4; ++nt)
      o[nt] = MFMA16(pf, vf[kc2][nt], o[nt]);
  }

  // write partials: bf16 O (contiguous 8 KB/block) + packed (m,l)
  const int slot = b * 272 + slot_off(qt) + c;
  short* Ob = OpartH + (size_t)slot * 4096;
#pragma unroll
  for (int nt = 0; nt < 4; ++nt)
#pragma unroll
    for (int r = 0; r < 4; ++r)
      Ob[(size_t)(w * 16 + quad * 4 + r) * AH + nt * 16 + lm] = f2bf(o[nt][r]);
  if (lm == 0) {
#pragma unroll
    for (int r = 0; r < 4; ++r)
      mlpart[(size_t)slot * 64 + w * 16 + quad * 4 + r] = make_float2(m_i[r], l_i[r]);
  }
}

// ---------------------------------------------------------------------------
// Kernel 3: merge via async LDS staging. grid (4 rowgroups, 32 qt, 4 b).
// ---------------------------------------------------------------------------
__global__ __launch_bounds__(256) void merge_kernel(const short* __restrict__ OpartH,
                                                    const float2* __restrict__ mlpart,
                                                    float* __restrict__ out) {
  __shared__ __align__(16) short ldsO[16 * 1024];  // [chunk(16)][row(16)][a(64)] bf16
  __shared__ float wtab[16][17];                   // [row][chunk] weight/L
  const int t = threadIdx.x;
  const int w = t >> 6, l = t & 63;
  const int rg = blockIdx.x, qt = blockIdx.y, b = blockIdx.z;
  const int r0 = rg * 16;
  const int nch = (qt >> 1) + 1;
  const int slotbase = b * 272 + slot_off(qt);

#pragma unroll
  for (int u = 0; u < 8; ++u) {
    int idx = w * 8 + u;  // 32 issues x 1 KB
    int c = idx >> 1, half = idx & 1;
    if (c < nch)  // wave-uniform predicate
      async16(OpartH + (size_t)(slotbase + c) * 4096 + r0 * 64 + half * 512 + l * 8,
              ldsO + c * 1024 + half * 512 + l * 8);
  }

  const int row = w * 4 + (l >> 4), c = l & 15;
  float mc = -INFINITY, lc = 0.f;
  if (c < nch) {
    float2 ml = mlpart[(size_t)(slotbase + c) * 64 + r0 + row];
    mc = ml.x; lc = ml.y;
  }
  float M = mc;
  for (int off = 1; off < 16; off <<= 1) M = fmaxf(M, __shfl_xor(M, off, 16));
  float wgt = (mc != -INFINITY) ? __expf(mc - M) : 0.f;
  float L = lc * wgt;
  for (int off = 1; off < 16; off <<= 1) L += __shfl_xor(L, off, 16);
  wtab[row][c] = wgt / L;

  __syncthreads();  // drains async staging; wtab visible

  const int row2 = t >> 4, a0 = (t & 15) * 4;
  float4 acc = make_float4(0.f, 0.f, 0.f, 0.f);
  for (int cc = 0; cc < nch; ++cc) {
    float wv = wtab[row2][cc];
    short4 v4 = *(const short4*)(ldsO + cc * 1024 + row2 * 64 + a0);
    acc.x += wv * bf2f(v4.x); acc.y += wv * bf2f(v4.y);
    acc.z += wv * bf2f(v4.z); acc.w += wv * bf2f(v4.w);
  }
  *(float4*)&out[((size_t)(b * 2048 + qt * 64 + r0 + row2)) * AH + a0] = acc;
}

// ---------------------------------------------------------------------------
// Workspace (bytes):
//   Kpack   [0,        3145728)    4 b x 16 chunks x 48 KB
//   BpkG    [3145728,  3670016)    256 KB (+slack)
//   OpartH  [3670016,  12582912)   1088 slots x 4096 bf16
//   mlpart  [12582912, 13139968)   1088 x 64 float2
// ---------------------------------------------------------------------------
extern "C" void kernel_launch(void* const* d_in, const int* in_sizes, int n_in,
                              void* d_out, int out_size, void* d_ws, size_t ws_size,
                              hipStream_t stream) {
  const float* emb = (const float*)d_in[0];
  const float* Wk  = (const float*)d_in[1];
  float* out = (float*)d_out;
  char* ws = (char*)d_ws;

  short*  Kpack  = (short*)(ws);
  short*  BpkG   = (short*)(ws + 3145728);
  short*  OpartH = (short*)(ws + 3670016);
  float2* mlpart = (float2*)(ws + 12582912);

  prep_wk_kernel<<<dim3(32), dim3(256), 0, stream>>>(Wk, BpkG);
  gemm_k_kernel<<<dim3(512), dim3(256), 0, stream>>>(emb, BpkG, Kpack);
  flash_kernel<<<dim3(16, 32, 4), dim3(256), 0, stream>>>(Kpack, OpartH, mlpart);
  merge_kernel<<<dim3(4, 32, 4), dim3(256), 0, stream>>>(OpartH, mlpart, out);
}

// Round 9
// 111.750 us; speedup vs baseline: 1.0220x; 1.0220x over previous
//
#include <hip/hip_runtime.h>
#include <math.h>

// Problem constants (B=4, S=2048, E=1024, A=64)
#define BATCH 4
#define SLEN  2048
#define EMB   1024
#define AH    64

typedef __attribute__((ext_vector_type(8))) short bf16x8;
typedef __attribute__((ext_vector_type(4))) float f32x4;

#define MFMA16(a, b, c) __builtin_amdgcn_mfma_f32_16x16x32_bf16((a), (b), (c), 0, 0, 0)

// async 16B global->LDS: zero VGPR cost, guaranteed in-flight batching.
// LDS dest = wave-uniform base + lane*16 (implicit).
__device__ __forceinline__ void async16(const void* g, void* l) {
  __builtin_amdgcn_global_load_lds(
      (const __attribute__((address_space(1))) unsigned int*)g,
      (__attribute__((address_space(3))) unsigned int*)l, 16, 0, 0);
}

__device__ __forceinline__ short f2bf(float x) {  // RNE
  union { float f; unsigned u; } v; v.f = x;
  unsigned r = v.u + 0x7fffu + ((v.u >> 16) & 1u);
  return (short)(r >> 16);
}
__device__ __forceinline__ float bf2f(short h) {
  union { unsigned u; float f; } v; v.u = ((unsigned)(unsigned short)h) << 16;
  return v.f;
}

// Truncate-split 8 fp32 -> bf16 hi (high16) + bf16 lo (trunc of residual).
__device__ __forceinline__ void split_trunc(float4 a0, float4 a1, bf16x8& hi, bf16x8& lo) {
  unsigned c[8] = {__float_as_uint(a0.x), __float_as_uint(a0.y), __float_as_uint(a0.z),
                   __float_as_uint(a0.w), __float_as_uint(a1.x), __float_as_uint(a1.y),
                   __float_as_uint(a1.z), __float_as_uint(a1.w)};
  union { bf16x8 v; unsigned d[4]; } H, L;
  H.d[0] = __builtin_amdgcn_perm(c[1], c[0], 0x07060302u);
  H.d[1] = __builtin_amdgcn_perm(c[3], c[2], 0x07060302u);
  H.d[2] = __builtin_amdgcn_perm(c[5], c[4], 0x07060302u);
  H.d[3] = __builtin_amdgcn_perm(c[7], c[6], 0x07060302u);
  unsigned e[8];
#pragma unroll
  for (int j = 0; j < 8; ++j)
    e[j] = __float_as_uint(__uint_as_float(c[j]) - __uint_as_float(c[j] & 0xffff0000u));
  L.d[0] = __builtin_amdgcn_perm(e[1], e[0], 0x07060302u);
  L.d[1] = __builtin_amdgcn_perm(e[3], e[2], 0x07060302u);
  L.d[2] = __builtin_amdgcn_perm(e[5], e[4], 0x07060302u);
  L.d[3] = __builtin_amdgcn_perm(e[7], e[6], 0x07060302u);
  hi = H.v; lo = L.v;
}

// Triangular chunk-slot offset: off(qt) = sum_{q<qt} (q/2 + 1)
__device__ __forceinline__ int slot_off(int qt) {
  return (qt == 0) ? 0 : qt + (((qt - 1) * (qt - 1)) >> 2);
}

// Kpack chunk layout (shorts), per (b, chunk of 128 keys), 24576 shorts = 48 KB:
//   [0,8192):      KBhi  [kb(8)][a32(2)][lane(64)][8]   S-MFMA B-frag, hi plane
//   [8192,16384):  KBlo  same, lo plane
//   [16384,24576): VB    [kc2(4)][nt(4)][lane(64)][8] PV-MFMA B-frag (hi only)
#define CH_SHORTS 24576

// ---------------------------------------------------------------------------
// 3-kernel serial pipeline.
// R7/R8 A/B results: one-barrier gemm = -1.8us (keep); hi-only flash = +8.8us
// (reverted to R0-exact flash). New this round: prep kernel ELIMINATED --
// each gemm lane loads its B-fragment (8 contiguous floats) directly from Wk
// and split_truncs inline. Bit-identical values to the BpkG path (same 8
// floats, same split); Wk (256 KB) is L2-resident. Removes one kernel + one
// inter-kernel drain.
// ---------------------------------------------------------------------------

// ---------------------------------------------------------------------------
// Kernel 1: K = emb @ Wk^T, ONE-BARRIER, self-contained (no prep).
// Stage ALL 16 K-step emb tiles up front (64 KB LDS, 16 async16/thread,
// single __syncthreads); B-fragments loaded per-lane from raw Wk + inline
// split_trunc. 64 KB LDS -> 2 blocks/CU; 512 blocks = one resident round.
// ---------------------------------------------------------------------------
__global__ __launch_bounds__(256) void gemm_k_kernel(const float* __restrict__ emb,
                                                     const float* __restrict__ Wk,
                                                     short* __restrict__ Kpack) {
  __shared__ __align__(16) float eT[16384];  // 64 KB: [s(16)][row(16)][64f swizzled]

  const int t = threadIdx.x;
  const int w = t >> 6, l = t & 63, lm = l & 15, quad = l >> 4;
  const int nt = w;
  const int row0 = blockIdx.x * 16;

  {  // stage: row rowl, swizzled du slot; dest = wave base + lane*16 (linear)
    int rowl = 4 * w + (l >> 4);
    int du = (l & 15) ^ (rowl & 7);
    const float* src = emb + (size_t)(row0 + rowl) * EMB + du * 4;
#pragma unroll
    for (int s = 0; s < 16; ++s)
      async16(src + s * 64, eT + s * 1024 + w * 256);
  }
  __syncthreads();  // the ONLY barrier: drains all 16 tiles

  // B-fragment source: row n = nt*16+lm of Wk; k = (2s+kc)*32 + quad*8.
  // Identical floats to prep's BpkG packing for (kcg=2s+kc, nt, lane=l).
  const float* wkB = Wk + (size_t)(nt * 16 + lm) * EMB + quad * 8;

  f32x4 acc = {0.f, 0.f, 0.f, 0.f};
#pragma unroll
  for (int s = 0; s < 16; ++s) {
    const char* eS = (const char*)(eT + s * 1024);
#pragma unroll
    for (int kc = 0; kc < 2; ++kc) {
      int du0 = kc * 8 + quad * 2;
      float4 a0 = *(const float4*)(eS + lm * 256 + ((du0) ^ (lm & 7)) * 16);
      float4 a1 = *(const float4*)(eS + lm * 256 + ((du0 + 1) ^ (lm & 7)) * 16);
      bf16x8 ahi, alo;
      split_trunc(a0, a1, ahi, alo);
      const float* bsrc = wkB + (s * 2 + kc) * 32;
      float4 b0 = *(const float4*)(bsrc);
      float4 b1 = *(const float4*)(bsrc + 4);
      bf16x8 bhi, blo;
      split_trunc(b0, b1, bhi, blo);
      acc = MFMA16(ahi, bhi, acc);
      acc = MFMA16(ahi, blo, acc);
      acc = MFMA16(alo, bhi, acc);
    }
  }

  // epilogue: C layout (row=quad*4+r, col a=nt*16+lm) -> Kpack fragment scatter
  const int a = nt * 16 + lm;
#pragma unroll
  for (int r = 0; r < 4; ++r) {
    int srow = row0 + quad * 4 + r;
    float v = acc[r];
    short h = f2bf(v);
    short lo2 = f2bf(v - bf2f(h));
    int bb = srow >> 11, si = srow & 2047, c = si >> 7, key = si & 127;
    int kb = key >> 4, klm = key & 15;
    size_t cb = (size_t)(bb * 16 + c) * CH_SHORTS;
    size_t kbo = (size_t)((kb * 2 + (a >> 5)) * 64 + ((a & 31) >> 3) * 16 + klm) * 8 + (a & 7);
    Kpack[cb + kbo] = h;
    Kpack[cb + 8192 + kbo] = lo2;
    size_t vbo = (size_t)(((key >> 5) * 4 + (a >> 4)) * 64 + ((key & 31) >> 3) * 16 + (a & 15)) * 8 + (key & 7);
    Kpack[cb + 16384 + vbo] = h;
  }
}

// ---------------------------------------------------------------------------
// Kernel 2 (R0-EXACT): flash partials. grid (16 chunks, 32 qt, 4 b); active
// iff 2c <= qt -> 1088 blocks (3/CU at 49.7 KB LDS). Stage KBhi+KBlo (32 KB);
// Q frags and all 16 V frags prefetched direct-to-VGPR before the barrier.
// ---------------------------------------------------------------------------
__global__ __launch_bounds__(256, 3) void flash_kernel(const short* __restrict__ Kpack,
                                                       short* __restrict__ OpartH,
                                                       float2* __restrict__ mlpart) {
  const int c = blockIdx.x, qt = blockIdx.y, b = blockIdx.z;
  if (2 * c > qt) return;

  __shared__ __align__(16) short KLs[16384];        // KBhi+KBlo of chunk c (32 KB)
  __shared__ __align__(16) short Plds[4][16][132];  // per-wave P buffers (16.5 KB)

  const int t = threadIdx.x;
  const int w = t >> 6, l = t & 63, lm = l & 15, quad = l >> 4;
  const int k0 = c * 128;
  const int qr0 = qt * 64 + w * 16;

  const short* chunkG = Kpack + (size_t)(b * 16 + c) * CH_SHORTS;
  // stage KBhi + KBlo: 32 slots x 1 KB
#pragma unroll
  for (int u = 0; u < 8; ++u) {
    int slot = w * 8 + u;
    async16(chunkG + slot * 512 + l * 8, KLs + slot * 512);
  }

  // Q fragments direct-to-VGPR (rows live in chunk qt>>1's KB region)
  const short* qG = Kpack + (size_t)(b * 16 + (qt >> 1)) * CH_SHORTS + ((qt & 1) * 4 + w) * 1024;
  bf16x8 qh0 = *(const bf16x8*)(qG + l * 8);
  bf16x8 qh1 = *(const bf16x8*)(qG + 512 + l * 8);
  bf16x8 ql0 = *(const bf16x8*)(qG + 8192 + l * 8);
  bf16x8 ql1 = *(const bf16x8*)(qG + 8192 + 512 + l * 8);

  // all 16 V fragments direct from global (coalesced 16B/lane)
  bf16x8 vf[4][4];
#pragma unroll
  for (int kc2 = 0; kc2 < 4; ++kc2)
#pragma unroll
    for (int nt = 0; nt < 4; ++nt)
      vf[kc2][nt] = *(const bf16x8*)(chunkG + 16384 + ((kc2 * 4 + nt) * 64 + l) * 8);

  __syncthreads();  // drains staging (Q/V register loads also complete)

  // S = Q K^T: 8 key-groups x 2 a-chunks x split(hh+hl+lh)
  f32x4 sc[8];
#pragma unroll
  for (int kg = 0; kg < 8; ++kg) {
    bf16x8 bh0 = *(const bf16x8*)(KLs + ((kg * 2 + 0) * 64 + l) * 8);
    bf16x8 bh1 = *(const bf16x8*)(KLs + ((kg * 2 + 1) * 64 + l) * 8);
    bf16x8 bl0 = *(const bf16x8*)(KLs + 8192 + ((kg * 2 + 0) * 64 + l) * 8);
    bf16x8 bl1 = *(const bf16x8*)(KLs + 8192 + ((kg * 2 + 1) * 64 + l) * 8);
    f32x4 s = {0.f, 0.f, 0.f, 0.f};
    s = MFMA16(qh0, bh0, s);
    s = MFMA16(qh0, bl0, s);
    s = MFMA16(ql0, bh0, s);
    s = MFMA16(qh1, bh1, s);
    s = MFMA16(qh1, bl1, s);
    s = MFMA16(ql1, bh1, s);
    sc[kg] = s;
  }

  // mask + single-pass softmax (C layout: row=quad*4+r, col=kg*16+lm)
  float rm[4] = {-INFINITY, -INFINITY, -INFINITY, -INFINITY};
#pragma unroll
  for (int kg = 0; kg < 8; ++kg) {
    const int col = k0 + kg * 16 + lm;
#pragma unroll
    for (int r = 0; r < 4; ++r) {
      const int row = qr0 + quad * 4 + r;
      float v = sc[kg][r] * 0.125f;
      v = (col > row || v == 0.0f) ? -INFINITY : v;
      sc[kg][r] = v;
      rm[r] = fmaxf(rm[r], v);
    }
  }
  float m_i[4], l_i[4];
#pragma unroll
  for (int r = 0; r < 4; ++r) {
    for (int off = 1; off < 16; off <<= 1) rm[r] = fmaxf(rm[r], __shfl_xor(rm[r], off, 16));
    m_i[r] = rm[r];
  }
  float rs[4] = {0.f, 0.f, 0.f, 0.f};
#pragma unroll
  for (int kg = 0; kg < 8; ++kg)
#pragma unroll
    for (int r = 0; r < 4; ++r) {
      float p = (sc[kg][r] == -INFINITY) ? 0.f : __expf(sc[kg][r] - m_i[r]);
      sc[kg][r] = p;
      rs[r] += p;
    }
#pragma unroll
  for (int r = 0; r < 4; ++r) {
    for (int off = 1; off < 16; off <<= 1) rs[r] += __shfl_xor(rs[r], off, 16);
    l_i[r] = rs[r];
  }

  // P -> Plds (C layout -> A-operand layout), per-wave private, no barrier
#pragma unroll
  for (int kg = 0; kg < 8; ++kg)
#pragma unroll
    for (int r = 0; r < 4; ++r)
      Plds[w][quad * 4 + r][kg * 16 + lm] = f2bf(sc[kg][r]);

  // O = P V over 128 keys (V fragments already in registers)
  f32x4 o[4] = {{0.f,0.f,0.f,0.f},{0.f,0.f,0.f,0.f},{0.f,0.f,0.f,0.f},{0.f,0.f,0.f,0.f}};
#pragma unroll
  for (int kc2 = 0; kc2 < 4; ++kc2) {
    bf16x8 pf = *(const bf16x8*)&Plds[w][lm][kc2 * 32 + quad * 8];
#pragma unroll
    for (int nt = 0; nt < 4; ++nt)
      o[nt] = MFMA16(pf, vf[kc2][nt], o[nt]);
  }

  // write partials: bf16 O (contiguous 8 KB/block) + packed (m,l)
  const int slot = b * 272 + slot_off(qt) + c;
  short* Ob = OpartH + (size_t)slot * 4096;
#pragma unroll
  for (int nt = 0; nt < 4; ++nt)
#pragma unroll
    for (int r = 0; r < 4; ++r)
      Ob[(size_t)(w * 16 + quad * 4 + r) * AH + nt * 16 + lm] = f2bf(o[nt][r]);
  if (lm == 0) {
#pragma unroll
    for (int r = 0; r < 4; ++r)
      mlpart[(size_t)slot * 64 + w * 16 + quad * 4 + r] = make_float2(m_i[r], l_i[r]);
  }
}

// ---------------------------------------------------------------------------
// Kernel 3: merge via async LDS staging. grid (4 rowgroups, 32 qt, 4 b).
// ---------------------------------------------------------------------------
__global__ __launch_bounds__(256) void merge_kernel(const short* __restrict__ OpartH,
                                                    const float2* __restrict__ mlpart,
                                                    float* __restrict__ out) {
  __shared__ __align__(16) short ldsO[16 * 1024];  // [chunk(16)][row(16)][a(64)] bf16
  __shared__ float wtab[16][17];                   // [row][chunk] weight/L
  const int t = threadIdx.x;
  const int w = t >> 6, l = t & 63;
  const int rg = blockIdx.x, qt = blockIdx.y, b = blockIdx.z;
  const int r0 = rg * 16;
  const int nch = (qt >> 1) + 1;
  const int slotbase = b * 272 + slot_off(qt);

#pragma unroll
  for (int u = 0; u < 8; ++u) {
    int idx = w * 8 + u;  // 32 issues x 1 KB
    int c = idx >> 1, half = idx & 1;
    if (c < nch)  // wave-uniform predicate
      async16(OpartH + (size_t)(slotbase + c) * 4096 + r0 * 64 + half * 512 + l * 8,
              ldsO + c * 1024 + half * 512 + l * 8);
  }

  const int row = w * 4 + (l >> 4), c = l & 15;
  float mc = -INFINITY, lc = 0.f;
  if (c < nch) {
    float2 ml = mlpart[(size_t)(slotbase + c) * 64 + r0 + row];
    mc = ml.x; lc = ml.y;
  }
  float M = mc;
  for (int off = 1; off < 16; off <<= 1) M = fmaxf(M, __shfl_xor(M, off, 16));
  float wgt = (mc != -INFINITY) ? __expf(mc - M) : 0.f;
  float L = lc * wgt;
  for (int off = 1; off < 16; off <<= 1) L += __shfl_xor(L, off, 16);
  wtab[row][c] = wgt / L;

  __syncthreads();  // drains async staging; wtab visible

  const int row2 = t >> 4, a0 = (t & 15) * 4;
  float4 acc = make_float4(0.f, 0.f, 0.f, 0.f);
  for (int cc = 0; cc < nch; ++cc) {
    float wv = wtab[row2][cc];
    short4 v4 = *(const short4*)(ldsO + cc * 1024 + row2 * 64 + a0);
    acc.x += wv * bf2f(v4.x); acc.y += wv * bf2f(v4.y);
    acc.z += wv * bf2f(v4.z); acc.w += wv * bf2f(v4.w);
  }
  *(float4*)&out[((size_t)(b * 2048 + qt * 64 + r0 + row2)) * AH + a0] = acc;
}

// ---------------------------------------------------------------------------
// Workspace (bytes):
//   Kpack   [0,        3145728)    4 b x 16 chunks x 48 KB
//   (gap    [3145728,  3670016)    former BpkG region, unused)
//   OpartH  [3670016,  12582912)   1088 slots x 4096 bf16
//   mlpart  [12582912, 13139968)   1088 x 64 float2
// ---------------------------------------------------------------------------
extern "C" void kernel_launch(void* const* d_in, const int* in_sizes, int n_in,
                              void* d_out, int out_size, void* d_ws, size_t ws_size,
                              hipStream_t stream) {
  const float* emb = (const float*)d_in[0];
  const float* Wk  = (const float*)d_in[1];
  float* out = (float*)d_out;
  char* ws = (char*)d_ws;

  short*  Kpack  = (short*)(ws);
  short*  OpartH = (short*)(ws + 3670016);
  float2* mlpart = (float2*)(ws + 12582912);

  gemm_k_kernel<<<dim3(512), dim3(256), 0, stream>>>(emb, Wk, Kpack);
  flash_kernel<<<dim3(16, 32, 4), dim3(256), 0, stream>>>(Kpack, OpartH, mlpart);
  merge_kernel<<<dim3(4, 32, 4), dim3(256), 0, stream>>>(OpartH, mlpart, out);
}

// Round 10
// 105.495 us; speedup vs baseline: 1.0826x; 1.0593x over previous
//
#include <hip/hip_runtime.h>
#include <math.h>

// Problem constants (B=4, S=2048, E=1024, A=64)
#define BATCH 4
#define SLEN  2048
#define EMB   1024
#define AH    64

typedef __attribute__((ext_vector_type(8))) short bf16x8;
typedef __attribute__((ext_vector_type(4))) float f32x4;

#define MFMA16(a, b, c) __builtin_amdgcn_mfma_f32_16x16x32_bf16((a), (b), (c), 0, 0, 0)

// async 16B global->LDS: zero VGPR cost, guaranteed in-flight batching.
// LDS dest = wave-uniform base + lane*16 (implicit).
__device__ __forceinline__ void async16(const void* g, void* l) {
  __builtin_amdgcn_global_load_lds(
      (const __attribute__((address_space(1))) unsigned int*)g,
      (__attribute__((address_space(3))) unsigned int*)l, 16, 0, 0);
}

__device__ __forceinline__ short f2bf(float x) {  // RNE
  union { float f; unsigned u; } v; v.f = x;
  unsigned r = v.u + 0x7fffu + ((v.u >> 16) & 1u);
  return (short)(r >> 16);
}
__device__ __forceinline__ float bf2f(short h) {
  union { unsigned u; float f; } v; v.u = ((unsigned)(unsigned short)h) << 16;
  return v.f;
}

// Truncate-split 8 fp32 -> bf16 hi (high16) + bf16 lo (trunc of residual).
__device__ __forceinline__ void split_trunc(float4 a0, float4 a1, bf16x8& hi, bf16x8& lo) {
  unsigned c[8] = {__float_as_uint(a0.x), __float_as_uint(a0.y), __float_as_uint(a0.z),
                   __float_as_uint(a0.w), __float_as_uint(a1.x), __float_as_uint(a1.y),
                   __float_as_uint(a1.z), __float_as_uint(a1.w)};
  union { bf16x8 v; unsigned d[4]; } H, L;
  H.d[0] = __builtin_amdgcn_perm(c[1], c[0], 0x07060302u);
  H.d[1] = __builtin_amdgcn_perm(c[3], c[2], 0x07060302u);
  H.d[2] = __builtin_amdgcn_perm(c[5], c[4], 0x07060302u);
  H.d[3] = __builtin_amdgcn_perm(c[7], c[6], 0x07060302u);
  unsigned e[8];
#pragma unroll
  for (int j = 0; j < 8; ++j)
    e[j] = __float_as_uint(__uint_as_float(c[j]) - __uint_as_float(c[j] & 0xffff0000u));
  L.d[0] = __builtin_amdgcn_perm(e[1], e[0], 0x07060302u);
  L.d[1] = __builtin_amdgcn_perm(e[3], e[2], 0x07060302u);
  L.d[2] = __builtin_amdgcn_perm(e[5], e[4], 0x07060302u);
  L.d[3] = __builtin_amdgcn_perm(e[7], e[6], 0x07060302u);
  hi = H.v; lo = L.v;
}

// Triangular chunk-slot offset: off(qt) = sum_{q<qt} (q/2 + 1)
__device__ __forceinline__ int slot_off(int qt) {
  return (qt == 0) ? 0 : qt + (((qt - 1) * (qt - 1)) >> 2);
}

// Kpack chunk layout (shorts), per (b, chunk of 128 keys), 24576 shorts = 48 KB:
//   [0,8192):      KBhi  [kb(8)][a32(2)][lane(64)][8]   S-MFMA B-frag, hi plane
//   [8192,16384):  KBlo  same, lo plane
//   [16384,24576): VB    [kc2(4)][nt(4)][lane(64)][8] PV-MFMA B-frag (hi only)
#define CH_SHORTS 24576

// ---------------------------------------------------------------------------
// Measured-best composition (A/B ledger, R7/R8/R9):
//   gemm: one-barrier + BpkG-fed (R7, -1.8us vs dbuf)   [inline-Wk was +8]
//   flash: R0-exact 3/CU full staging                   [4/CU hi-only was +8.8]
//   prep/merge: R0-exact.
// ---------------------------------------------------------------------------

// ---------------------------------------------------------------------------
// Kernel 0: pack Wk [64,1024] fp32 -> BpkG [kc(32)][nt(4)][pl(2)][lane(64)][8]
// ---------------------------------------------------------------------------
__global__ __launch_bounds__(256) void prep_wk_kernel(const float* __restrict__ Wk,
                                                      short* __restrict__ BpkG) {
  int tg = blockIdx.x * 256 + threadIdx.x;  // 8192 = 32kc * 4nt * 64lane
  int kc = tg >> 8, rem = tg & 255, nt = rem >> 6, lane = rem & 63;
  int n = nt * 16 + (lane & 15);
  int k = kc * 32 + (lane >> 4) * 8;
  const float* src = Wk + (size_t)n * EMB + k;
  float4 a0 = *(const float4*)src;
  float4 a1 = *(const float4*)(src + 4);
  bf16x8 hi, lo;
  split_trunc(a0, a1, hi, lo);
  short* dst = BpkG + ((size_t)(kc * 4 + nt) * 128 + lane) * 8;  // pl=0
  *(bf16x8*)dst = hi;
  *(bf16x8*)(dst + 512) = lo;  // pl=1
}

// ---------------------------------------------------------------------------
// Kernel 1 (R7-validated): K = emb @ Wk^T, ONE-BARRIER.
// Stage ALL 16 K-step emb tiles up front (64 KB LDS, 16 async16/thread,
// single __syncthreads), then 16 pure compute steps with B-fragments read
// DIRECTLY from BpkG (L2-resident 256 KB; coalesced 1KB/wave-instr; no
// barrier dependency -> compiler pipelines). 64 KB LDS -> 2 blocks/CU;
// 512 blocks = one resident round.
// ---------------------------------------------------------------------------
__global__ __launch_bounds__(256) void gemm_k_kernel(const float* __restrict__ emb,
                                                     const short* __restrict__ BpkG,
                                                     short* __restrict__ Kpack) {
  __shared__ __align__(16) float eT[16384];  // 64 KB: [s(16)][row(16)][64f swizzled]

  const int t = threadIdx.x;
  const int w = t >> 6, l = t & 63, lm = l & 15, quad = l >> 4;
  const int nt = w;
  const int row0 = blockIdx.x * 16;

  {  // stage: row rowl, swizzled du slot; dest = wave base + lane*16 (linear)
    int rowl = 4 * w + (l >> 4);
    int du = (l & 15) ^ (rowl & 7);
    const float* src = emb + (size_t)(row0 + rowl) * EMB + du * 4;
#pragma unroll
    for (int s = 0; s < 16; ++s)
      async16(src + s * 64, eT + s * 1024 + w * 256);
  }
  __syncthreads();  // the ONLY barrier: drains all 16 tiles

  f32x4 acc = {0.f, 0.f, 0.f, 0.f};
#pragma unroll
  for (int s = 0; s < 16; ++s) {
    const char* eS = (const char*)(eT + s * 1024);
    const short* bg = BpkG + (size_t)s * 8192;
#pragma unroll
    for (int kc = 0; kc < 2; ++kc) {
      int du0 = kc * 8 + quad * 2;
      float4 a0 = *(const float4*)(eS + lm * 256 + ((du0) ^ (lm & 7)) * 16);
      float4 a1 = *(const float4*)(eS + lm * 256 + ((du0 + 1) ^ (lm & 7)) * 16);
      bf16x8 ahi, alo;
      split_trunc(a0, a1, ahi, alo);
      bf16x8 bhi = *(const bf16x8*)(bg + (((kc * 4 + nt) * 2 + 0) * 64 + l) * 8);
      bf16x8 blo = *(const bf16x8*)(bg + (((kc * 4 + nt) * 2 + 1) * 64 + l) * 8);
      acc = MFMA16(ahi, bhi, acc);
      acc = MFMA16(ahi, blo, acc);
      acc = MFMA16(alo, bhi, acc);
    }
  }

  // epilogue: C layout (row=quad*4+r, col a=nt*16+lm) -> Kpack fragment scatter
  const int a = nt * 16 + lm;
#pragma unroll
  for (int r = 0; r < 4; ++r) {
    int srow = row0 + quad * 4 + r;
    float v = acc[r];
    short h = f2bf(v);
    short lo2 = f2bf(v - bf2f(h));
    int bb = srow >> 11, si = srow & 2047, c = si >> 7, key = si & 127;
    int kb = key >> 4, klm = key & 15;
    size_t cb = (size_t)(bb * 16 + c) * CH_SHORTS;
    size_t kbo = (size_t)((kb * 2 + (a >> 5)) * 64 + ((a & 31) >> 3) * 16 + klm) * 8 + (a & 7);
    Kpack[cb + kbo] = h;
    Kpack[cb + 8192 + kbo] = lo2;
    size_t vbo = (size_t)(((key >> 5) * 4 + (a >> 4)) * 64 + ((key & 31) >> 3) * 16 + (a & 15)) * 8 + (key & 7);
    Kpack[cb + 16384 + vbo] = h;
  }
}

// ---------------------------------------------------------------------------
// Kernel 2 (R0-EXACT): flash partials. grid (16 chunks, 32 qt, 4 b); active
// iff 2c <= qt -> 1088 blocks (3/CU at 49.7 KB LDS). Stage KBhi+KBlo (32 KB);
// Q frags and all 16 V frags prefetched direct-to-VGPR before the barrier.
// ---------------------------------------------------------------------------
__global__ __launch_bounds__(256, 3) void flash_kernel(const short* __restrict__ Kpack,
                                                       short* __restrict__ OpartH,
                                                       float2* __restrict__ mlpart) {
  const int c = blockIdx.x, qt = blockIdx.y, b = blockIdx.z;
  if (2 * c > qt) return;

  __shared__ __align__(16) short KLs[16384];        // KBhi+KBlo of chunk c (32 KB)
  __shared__ __align__(16) short Plds[4][16][132];  // per-wave P buffers (16.5 KB)

  const int t = threadIdx.x;
  const int w = t >> 6, l = t & 63, lm = l & 15, quad = l >> 4;
  const int k0 = c * 128;
  const int qr0 = qt * 64 + w * 16;

  const short* chunkG = Kpack + (size_t)(b * 16 + c) * CH_SHORTS;
  // stage KBhi + KBlo: 32 slots x 1 KB
#pragma unroll
  for (int u = 0; u < 8; ++u) {
    int slot = w * 8 + u;
    async16(chunkG + slot * 512 + l * 8, KLs + slot * 512);
  }

  // Q fragments direct-to-VGPR (rows live in chunk qt>>1's KB region)
  const short* qG = Kpack + (size_t)(b * 16 + (qt >> 1)) * CH_SHORTS + ((qt & 1) * 4 + w) * 1024;
  bf16x8 qh0 = *(const bf16x8*)(qG + l * 8);
  bf16x8 qh1 = *(const bf16x8*)(qG + 512 + l * 8);
  bf16x8 ql0 = *(const bf16x8*)(qG + 8192 + l * 8);
  bf16x8 ql1 = *(const bf16x8*)(qG + 8192 + 512 + l * 8);

  // all 16 V fragments direct from global (coalesced 16B/lane)
  bf16x8 vf[4][4];
#pragma unroll
  for (int kc2 = 0; kc2 < 4; ++kc2)
#pragma unroll
    for (int nt = 0; nt < 4; ++nt)
      vf[kc2][nt] = *(const bf16x8*)(chunkG + 16384 + ((kc2 * 4 + nt) * 64 + l) * 8);

  __syncthreads();  // drains staging (Q/V register loads also complete)

  // S = Q K^T: 8 key-groups x 2 a-chunks x split(hh+hl+lh)
  f32x4 sc[8];
#pragma unroll
  for (int kg = 0; kg < 8; ++kg) {
    bf16x8 bh0 = *(const bf16x8*)(KLs + ((kg * 2 + 0) * 64 + l) * 8);
    bf16x8 bh1 = *(const bf16x8*)(KLs + ((kg * 2 + 1) * 64 + l) * 8);
    bf16x8 bl0 = *(const bf16x8*)(KLs + 8192 + ((kg * 2 + 0) * 64 + l) * 8);
    bf16x8 bl1 = *(const bf16x8*)(KLs + 8192 + ((kg * 2 + 1) * 64 + l) * 8);
    f32x4 s = {0.f, 0.f, 0.f, 0.f};
    s = MFMA16(qh0, bh0, s);
    s = MFMA16(qh0, bl0, s);
    s = MFMA16(ql0, bh0, s);
    s = MFMA16(qh1, bh1, s);
    s = MFMA16(qh1, bl1, s);
    s = MFMA16(ql1, bh1, s);
    sc[kg] = s;
  }

  // mask + single-pass softmax (C layout: row=quad*4+r, col=kg*16+lm)
  float rm[4] = {-INFINITY, -INFINITY, -INFINITY, -INFINITY};
#pragma unroll
  for (int kg = 0; kg < 8; ++kg) {
    const int col = k0 + kg * 16 + lm;
#pragma unroll
    for (int r = 0; r < 4; ++r) {
      const int row = qr0 + quad * 4 + r;
      float v = sc[kg][r] * 0.125f;
      v = (col > row || v == 0.0f) ? -INFINITY : v;
      sc[kg][r] = v;
      rm[r] = fmaxf(rm[r], v);
    }
  }
  float m_i[4], l_i[4];
#pragma unroll
  for (int r = 0; r < 4; ++r) {
    for (int off = 1; off < 16; off <<= 1) rm[r] = fmaxf(rm[r], __shfl_xor(rm[r], off, 16));
    m_i[r] = rm[r];
  }
  float rs[4] = {0.f, 0.f, 0.f, 0.f};
#pragma unroll
  for (int kg = 0; kg < 8; ++kg)
#pragma unroll
    for (int r = 0; r < 4; ++r) {
      float p = (sc[kg][r] == -INFINITY) ? 0.f : __expf(sc[kg][r] - m_i[r]);
      sc[kg][r] = p;
      rs[r] += p;
    }
#pragma unroll
  for (int r = 0; r < 4; ++r) {
    for (int off = 1; off < 16; off <<= 1) rs[r] += __shfl_xor(rs[r], off, 16);
    l_i[r] = rs[r];
  }

  // P -> Plds (C layout -> A-operand layout), per-wave private, no barrier
#pragma unroll
  for (int kg = 0; kg < 8; ++kg)
#pragma unroll
    for (int r = 0; r < 4; ++r)
      Plds[w][quad * 4 + r][kg * 16 + lm] = f2bf(sc[kg][r]);

  // O = P V over 128 keys (V fragments already in registers)
  f32x4 o[4] = {{0.f,0.f,0.f,0.f},{0.f,0.f,0.f,0.f},{0.f,0.f,0.f,0.f},{0.f,0.f,0.f,0.f}};
#pragma unroll
  for (int kc2 = 0; kc2 < 4; ++kc2) {
    bf16x8 pf = *(const bf16x8*)&Plds[w][lm][kc2 * 32 + quad * 8];
#pragma unroll
    for (int nt = 0; nt < 4; ++nt)
      o[nt] = MFMA16(pf, vf[kc2][nt], o[nt]);
  }

  // write partials: bf16 O (contiguous 8 KB/block) + packed (m,l)
  const int slot = b * 272 + slot_off(qt) + c;
  short* Ob = OpartH + (size_t)slot * 4096;
#pragma unroll
  for (int nt = 0; nt < 4; ++nt)
#pragma unroll
    for (int r = 0; r < 4; ++r)
      Ob[(size_t)(w * 16 + quad * 4 + r) * AH + nt * 16 + lm] = f2bf(o[nt][r]);
  if (lm == 0) {
#pragma unroll
    for (int r = 0; r < 4; ++r)
      mlpart[(size_t)slot * 64 + w * 16 + quad * 4 + r] = make_float2(m_i[r], l_i[r]);
  }
}

// ---------------------------------------------------------------------------
// Kernel 3: merge via async LDS staging. grid (4 rowgroups, 32 qt, 4 b).
// ---------------------------------------------------------------------------
__global__ __launch_bounds__(256) void merge_kernel(const short* __restrict__ OpartH,
                                                    const float2* __restrict__ mlpart,
                                                    float* __restrict__ out) {
  __shared__ __align__(16) short ldsO[16 * 1024];  // [chunk(16)][row(16)][a(64)] bf16
  __shared__ float wtab[16][17];                   // [row][chunk] weight/L
  const int t = threadIdx.x;
  const int w = t >> 6, l = t & 63;
  const int rg = blockIdx.x, qt = blockIdx.y, b = blockIdx.z;
  const int r0 = rg * 16;
  const int nch = (qt >> 1) + 1;
  const int slotbase = b * 272 + slot_off(qt);

#pragma unroll
  for (int u = 0; u < 8; ++u) {
    int idx = w * 8 + u;  // 32 issues x 1 KB
    int c = idx >> 1, half = idx & 1;
    if (c < nch)  // wave-uniform predicate
      async16(OpartH + (size_t)(slotbase + c) * 4096 + r0 * 64 + half * 512 + l * 8,
              ldsO + c * 1024 + half * 512 + l * 8);
  }

  const int row = w * 4 + (l >> 4), c = l & 15;
  float mc = -INFINITY, lc = 0.f;
  if (c < nch) {
    float2 ml = mlpart[(size_t)(slotbase + c) * 64 + r0 + row];
    mc = ml.x; lc = ml.y;
  }
  float M = mc;
  for (int off = 1; off < 16; off <<= 1) M = fmaxf(M, __shfl_xor(M, off, 16));
  float wgt = (mc != -INFINITY) ? __expf(mc - M) : 0.f;
  float L = lc * wgt;
  for (int off = 1; off < 16; off <<= 1) L += __shfl_xor(L, off, 16);
  wtab[row][c] = wgt / L;

  __syncthreads();  // drains async staging; wtab visible

  const int row2 = t >> 4, a0 = (t & 15) * 4;
  float4 acc = make_float4(0.f, 0.f, 0.f, 0.f);
  for (int cc = 0; cc < nch; ++cc) {
    float wv = wtab[row2][cc];
    short4 v4 = *(const short4*)(ldsO + cc * 1024 + row2 * 64 + a0);
    acc.x += wv * bf2f(v4.x); acc.y += wv * bf2f(v4.y);
    acc.z += wv * bf2f(v4.z); acc.w += wv * bf2f(v4.w);
  }
  *(float4*)&out[((size_t)(b * 2048 + qt * 64 + r0 + row2)) * AH + a0] = acc;
}

// ---------------------------------------------------------------------------
// Workspace (bytes):
//   Kpack   [0,        3145728)    4 b x 16 chunks x 48 KB
//   BpkG    [3145728,  3670016)    256 KB (+slack)
//   OpartH  [3670016,  12582912)   1088 slots x 4096 bf16
//   mlpart  [12582912, 13139968)   1088 x 64 float2
// ---------------------------------------------------------------------------
extern "C" void kernel_launch(void* const* d_in, const int* in_sizes, int n_in,
                              void* d_out, int out_size, void* d_ws, size_t ws_size,
                              hipStream_t stream) {
  const float* emb = (const float*)d_in[0];
  const float* Wk  = (const float*)d_in[1];
  float* out = (float*)d_out;
  char* ws = (char*)d_ws;

  short*  Kpack  = (short*)(ws);
  short*  BpkG   = (short*)(ws + 3145728);
  short*  OpartH = (short*)(ws + 3670016);
  float2* mlpart = (float2*)(ws + 12582912);

  prep_wk_kernel<<<dim3(32), dim3(256), 0, stream>>>(Wk, BpkG);
  gemm_k_kernel<<<dim3(512), dim3(256), 0, stream>>>(emb, BpkG, Kpack);
  flash_kernel<<<dim3(16, 32, 4), dim3(256), 0, stream>>>(Kpack, OpartH, mlpart);
  merge_kernel<<<dim3(4, 32, 4), dim3(256), 0, stream>>>(OpartH, mlpart, out);
}